// Round 7
// baseline (113.346 us; speedup 1.0000x reference)
//
#include <hip/hip_runtime.h>
#include <hip/hip_bf16.h>

// LearnableChebyshevKernelAttention, MI355X — 2-dispatch version.
// prep: values -> Vt bf16, out_w -> Wb bf16, zero group counters.
// cheb_attn(+proj tail): verified R3 cheb body (scalar Chebyshev scores in
// MFMA A-frag layout, barrier-free main loop); after writing its flat slice
// each block does release-fetch_add on its (b,qt) group counter; the 8th
// (last) block acquire-loads and computes the 32x512 out-projection for the
// group with the SAME MFMA accumulation order as the old proj kernel
// (bit-identical numerics). No grid.sync (measured ~55us/sync), no spinning.
// Dispatch overhead measured ~6us/boundary -> merging proj saves ~8us.
// B=2, Q=M=1024, DIM=3, H=8, V=64, OUT=512, C=8.

typedef __attribute__((ext_vector_type(8))) short short8v;
typedef __attribute__((ext_vector_type(4))) short short4v;
typedef __attribute__((ext_vector_type(4))) float f32x4;

#define EPSF 1e-5f

__device__ __forceinline__ float frcp(float x) { return __builtin_amdgcn_rcpf(x); }
__device__ __forceinline__ short f2bf(float f) {
    __hip_bfloat16 h = __float2bfloat16(f);   // RNE
    return *reinterpret_cast<short*>(&h);
}

// ws layout (shorts): Vt bf16 [2*8*64*1024] | Wb bf16 [512*512]
//                     | flat bf16 [2*1024*512] | cnt int[64]
#define VT_ELEMS   (2u * 8u * 64u * 1024u)
#define WB_OFF_S   (VT_ELEMS)
#define FLAT_OFF_S (VT_ELEMS + 512u * 512u)
#define CNT_OFF_S  (FLAT_OFF_S + 2u * 1024u * 512u)   // 4B-aligned (even short idx)

// ---------------------------------------------------------------- prep
// grid 288: blocks 0..255 transpose one (b,h,64m) values tile; 256..287
// convert W; block 256 also zeroes the 64 group counters.
__global__ __launch_bounds__(256) void prep(
    const float* __restrict__ vals, const float* __restrict__ outw,
    short* __restrict__ vt, short* __restrict__ wb, int* __restrict__ cnt)
{
    const int bid = blockIdx.x, t = threadIdx.x;
    if (bid < 256) {
        __shared__ float sf[64 * 68];
        const int b = bid >> 7, h = (bid >> 4) & 7, m0 = (bid & 15) * 64;
        #pragma unroll
        for (int fi = 0; fi < 4; ++fi) {
            const int idx = fi * 256 + t, mr = idx >> 4, c4 = idx & 15;
            const float4 v4 = *(const float4*)&vals[
                (((size_t)b * 1024 + m0 + mr) * 8 + h) * 64 + c4 * 4];
            *(float4*)&sf[mr * 68 + c4 * 4] = v4;
        }
        __syncthreads();
        const int v = t >> 2, mo = t & 3;
        short8v o0, o1;
        #pragma unroll
        for (int i = 0; i < 8; ++i) o0[i] = f2bf(sf[(mo * 16 + i) * 68 + v]);
        #pragma unroll
        for (int i = 0; i < 8; ++i) o1[i] = f2bf(sf[(mo * 16 + 8 + i) * 68 + v]);
        const size_t ob = ((size_t)(b * 8 + h) * 64 + v) * 1024 + m0 + mo * 16;
        *(short8v*)&vt[ob] = o0;
        *(short8v*)&vt[ob + 8] = o1;
    } else {
        const int wi = bid - 256;            // 0..31, 8192 floats each
        if (wi == 0 && t < 64) cnt[t] = 0;   // zero group counters (ws is poisoned)
        #pragma unroll
        for (int k = 0; k < 8; ++k) {
            const int fidx = wi * 8192 + k * 1024 + t * 4;
            const float4 f4 = *(const float4*)&outw[fidx];
            short4v s; s[0] = f2bf(f4.x); s[1] = f2bf(f4.y);
                       s[2] = f2bf(f4.z); s[3] = f2bf(f4.w);
            *(short4v*)&wb[fidx] = s;
        }
    }
}

// ---------------------------------------------------------------- cheb_attn
// grid (32, 8, 2) = (qt, h, b), block 512 (8 waves), 2 blocks/CU.
__global__ __launch_bounds__(512, 4) void cheb_attn(
    const float* __restrict__ qp, const float* __restrict__ kp,
    const unsigned char* __restrict__ msk,
    const float* __restrict__ ls, const float* __restrict__ cheb,
    const short* __restrict__ vt, short* __restrict__ flatb,
    const short* __restrict__ wb, float* __restrict__ out,
    int* __restrict__ cnt)
{
    __shared__ float s_kx[1024], s_ky[1024], s_kz[1024];   // kp SoA
    __shared__ __align__(8) unsigned char s_mask[1024];
    __shared__ float s_l1[4][32];
    __shared__ float s_pb[3][32 * 68];                      // groups 1..3 partial P
    __shared__ int s_last;

    const int t = threadIdx.x;
    const int qt = blockIdx.x, h = blockIdx.y, b = blockIdx.z;
    const int w = t >> 6, lane = t & 63;
    const int wg = w & 1, g = w >> 1;          // q band (16 rows), m group (256 m)
    const int arow = lane & 15, koct = lane >> 4;

    // stage kp (SoA) + mask
    #pragma unroll
    for (int mm_ = 0; mm_ < 2; ++mm_) {
        const int m = mm_ * 512 + t;
        const size_t base = ((size_t)b * 1024 + m) * 3;
        s_kx[m] = kp[base + 0];
        s_ky[m] = kp[base + 1];
        s_kz[m] = kp[base + 2];
    }
    *(unsigned short*)&s_mask[t * 2] =
        *(const unsigned short*)&msk[(size_t)b * 1024 + t * 2];

    // per-head constants (wave-uniform -> scalar regs). Verified numerics.
    const float lsv = ls[h];
    const float invls2 = 1.0f / (lsv * lsv);
    float cc[8]; float cs = 0.f;
    #pragma unroll
    for (int j = 0; j < 8; ++j) { cc[j] = cheb[h * 8 + j]; cs += cc[j]; }
    const float cm = cs * 0.125f;
    #pragma unroll
    for (int j = 0; j < 8; ++j) cc[j] -= cm;

    // this lane's q row (A-fragment row identity)
    const int qg = qt * 32 + wg * 16 + arow;
    const float qx = qp[((size_t)b * 1024 + qg) * 3 + 0];
    const float qy = qp[((size_t)b * 1024 + qg) * 3 + 1];
    const float qz = qp[((size_t)b * 1024 + qg) * 3 + 2];

    f32x4 acc[4] = {(f32x4)(0.f), (f32x4)(0.f), (f32x4)(0.f), (f32x4)(0.f)};
    const short* vtb = vt + ((size_t)(b * 8 + h) * 64) * 1024;
    float l1p = 0.f;

    __syncthreads();   // kp/mask staged

    #pragma unroll
    for (int tile = 0; tile < 4; ++tile) {
        const int m0 = g * 256 + tile * 64;

        // ---- 1) issue Vt B-frag loads (L2) — consumed only at step 3
        short8v bfr[2][4];
        #pragma unroll
        for (int kk = 0; kk < 2; ++kk)
            #pragma unroll
            for (int f = 0; f < 4; ++f)
                bfr[kk][f] = *(const short8v*)
                    &vtb[(size_t)(f * 16 + arow) * 1024 + m0 + kk * 32 + koct * 8];

        // ---- 1b) issue LDS k reads + mask for both kk groups
        f32x4 kx[2][2], ky[2][2], kz[2][2];
        uint2 mmv[2];
        #pragma unroll
        for (int kk = 0; kk < 2; ++kk) {
            const int mb = m0 + kk * 32 + koct * 8;
            kx[kk][0] = *(const f32x4*)&s_kx[mb]; kx[kk][1] = *(const f32x4*)&s_kx[mb + 4];
            ky[kk][0] = *(const f32x4*)&s_ky[mb]; ky[kk][1] = *(const f32x4*)&s_ky[mb + 4];
            kz[kk][0] = *(const f32x4*)&s_kz[mb]; kz[kk][1] = *(const f32x4*)&s_kz[mb + 4];
            mmv[kk] = *(const uint2*)&s_mask[mb];
        }

        // ---- 2) 16 scores, verified Chebyshev-recurrence numerics
        short8v a[2];
        #pragma unroll
        for (int kk = 0; kk < 2; ++kk) {
            const bool anymask = (mmv[kk].x | mmv[kk].y) != 0u;
            #pragma unroll
            for (int j = 0; j < 8; ++j) {
                const float dx = qx - kx[kk][j >> 2][j & 3];
                const float dy = qy - ky[kk][j >> 2][j & 3];
                const float dz = qz - kz[kk][j >> 2][j & 3];
                const float x  = (dx * dx + dy * dy + dz * dz) * invls2;
                const float r  = (x - 1.f) * frcp(x + 1.f);
                const float r2 = r + r;
                float tp = 1.f, tc = r;
                float s  = cc[0] + cc[1] * r;
                #pragma unroll
                for (int c = 2; c < 8; ++c) {
                    const float tn = r2 * tc - tp;
                    s += cc[c] * tn; tp = tc; tc = tn;
                }
                if (anymask) {
                    const unsigned int mword = (j < 4) ? mmv[kk].x : mmv[kk].y;
                    if ((mword >> ((j & 3) * 8)) & 0xffu) s = 0.f;
                }
                l1p += fabsf(s);
                a[kk][j] = f2bf(s);
            }
        }

        // ---- 3) attend
        #pragma unroll
        for (int kk = 0; kk < 2; ++kk)
            #pragma unroll
            for (int f = 0; f < 4; ++f)
                acc[f] = __builtin_amdgcn_mfma_f32_16x16x32_bf16(
                    a[kk], bfr[kk][f], acc[f], 0, 0, 0);
    }

    // L1 partial: lanes {arow, arow+16, arow+32, arow+48} share q row
    l1p += __shfl_xor(l1p, 16);
    l1p += __shfl_xor(l1p, 32);
    if (koct == 0) s_l1[g][wg * 16 + arow] = l1p;

    if (g > 0) {
        #pragma unroll
        for (int f = 0; f < 4; ++f)
            #pragma unroll
            for (int j = 0; j < 4; ++j)
                s_pb[g - 1][(wg * 16 + koct * 4 + j) * 68 + f * 16 + arow] = acc[f][j];
    }
    __syncthreads();
    if (g == 0) {
        float rden[4];
        #pragma unroll
        for (int j = 0; j < 4; ++j) {
            const int row = wg * 16 + koct * 4 + j;
            rden[j] = frcp(s_l1[0][row] + s_l1[1][row] + s_l1[2][row]
                         + s_l1[3][row] + EPSF);
        }
        #pragma unroll
        for (int f = 0; f < 4; ++f)
            #pragma unroll
            for (int j = 0; j < 4; ++j) {
                const int row = wg * 16 + koct * 4 + j;
                const int col = f * 16 + arow;
                const float v = (acc[f][j]
                    + s_pb[0][row * 68 + col]
                    + s_pb[1][row * 68 + col]
                    + s_pb[2][row * 68 + col]) * rden[j];
                flatb[((size_t)b * 1024 + qt * 32 + row) * 512 + h * 64 + col]
                    = f2bf(v);
            }
    }

    // ---- 8-producer join on group (b,qt): last block projects the 32 rows.
    __syncthreads();                     // all flat stores of this block issued+drained
    if (t == 0) {
        __threadfence();                 // device-scope release of flat writes
        const int grp = b * 32 + qt;
        const int prev = __hip_atomic_fetch_add(&cnt[grp], 1,
                             __ATOMIC_RELEASE, __HIP_MEMORY_SCOPE_AGENT);
        int last = 0;
        if (prev == 7) {
            (void)__hip_atomic_load(&cnt[grp], __ATOMIC_ACQUIRE,
                                    __HIP_MEMORY_SCOPE_AGENT);  // inv L2
            last = 1;
        }
        s_last = last;
    }
    __syncthreads();
    if (!s_last) return;

    // ---- proj tail: out[b, qt*32..+32, :] = flat_rows @ Wb^T.
    // Same MFMA accumulation order as the old proj kernel -> bit-identical.
    const int rb = w & 1, ng = w >> 1;           // row band (16), n range (128)
    f32x4 pacc[8] = {(f32x4)(0.f), (f32x4)(0.f), (f32x4)(0.f), (f32x4)(0.f),
                     (f32x4)(0.f), (f32x4)(0.f), (f32x4)(0.f), (f32x4)(0.f)};
    const short* ap = &flatb[((size_t)b * 1024 + qt * 32 + rb * 16 + arow) * 512];
    #pragma unroll 4
    for (int kk2 = 0; kk2 < 16; ++kk2) {
        const int ko = kk2 * 32 + koct * 8;
        const short8v af = *(const short8v*)&ap[ko];
        #pragma unroll
        for (int nt = 0; nt < 8; ++nt) {
            const short8v bf = *(const short8v*)
                &wb[(size_t)(ng * 128 + nt * 16 + arow) * 512 + ko];
            pacc[nt] = __builtin_amdgcn_mfma_f32_16x16x32_bf16(af, bf, pacc[nt], 0, 0, 0);
        }
    }
    #pragma unroll
    for (int nt = 0; nt < 8; ++nt)
        #pragma unroll
        for (int j = 0; j < 4; ++j)
            out[((size_t)b * 1024 + qt * 32 + rb * 16 + koct * 4 + j) * 512
                + ng * 128 + nt * 16 + arow] = pacc[nt][j];
}

extern "C" void kernel_launch(void* const* d_in, const int* in_sizes, int n_in,
                              void* d_out, int out_size, void* d_ws, size_t ws_size,
                              hipStream_t stream) {
    const float* qp   = (const float*)d_in[0];
    const float* kp   = (const float*)d_in[1];
    const float* vals = (const float*)d_in[2];
    const unsigned char* msk = (const unsigned char*)d_in[3];
    const float* ls   = (const float*)d_in[4];
    const float* cheb = (const float*)d_in[5];
    const float* outw = (const float*)d_in[6];
    float* out = (float*)d_out;

    short* vtp   = (short*)d_ws;
    short* wbp   = vtp + WB_OFF_S;
    short* flatb = vtp + FLAT_OFF_S;
    int*   cnt   = (int*)(vtp + CNT_OFF_S);

    prep<<<288, 256, 0, stream>>>(vals, outw, vtp, wbp, cnt);
    cheb_attn<<<dim3(32, 8, 2), 512, 0, stream>>>(qp, kp, msk, ls, cheb,
                                                  vtp, flatb, wbp, out, cnt);
}

// Round 8
// 58.277 us; speedup vs baseline: 1.9450x; 1.9450x over previous
//
#include <hip/hip_runtime.h>
#include <hip/hip_bf16.h>

// LearnableChebyshevKernelAttention, MI355X — three-dispatch chain (fusion via
// grid.sync or per-block device fences measured catastrophic: both require
// cross-XCD L2 coherence ops, +55..+90us). cheb restructured for occupancy:
// grid (64,8,2)=1024 blocks, 512 thr, wave = one 16-q band x 128 m (2 tiles).
// LDS union {kp-SoA | epilogue partials} -> 35KB -> 4 blocks/CU = 8 waves/SIMD
// (2x latency hiding vs R3), half the per-wave critical path. Hot-loop score
// numerics BYTE-IDENTICAL to verified R3 (absmax 1.95e-3); epilogue combines
// 8 m-partials instead of 4 (f32 reassociation only).
// B=2, Q=M=1024, DIM=3, H=8, V=64, OUT=512, C=8.

typedef __attribute__((ext_vector_type(8))) short short8v;
typedef __attribute__((ext_vector_type(4))) short short4v;
typedef __attribute__((ext_vector_type(4))) float f32x4;

#define EPSF 1e-5f

__device__ __forceinline__ float frcp(float x) { return __builtin_amdgcn_rcpf(x); }
__device__ __forceinline__ short f2bf(float f) {
    __hip_bfloat16 h = __float2bfloat16(f);   // RNE
    return *reinterpret_cast<short*>(&h);
}

// ws layout (shorts): Vt bf16 [2*8*64*1024] | Wb bf16 [512*512] | flat bf16 [2*1024*512]
#define VT_ELEMS   (2u * 8u * 64u * 1024u)
#define WB_OFF_S   (VT_ELEMS)
#define FLAT_OFF_S (VT_ELEMS + 512u * 512u)

// ---------------------------------------------------------------- prep
// grid 288: blocks 0..255 transpose one (b,h,64m) values tile; 256..287 convert W.
__global__ __launch_bounds__(256) void prep(
    const float* __restrict__ vals, const float* __restrict__ outw,
    short* __restrict__ vt, short* __restrict__ wb)
{
    const int bid = blockIdx.x, t = threadIdx.x;
    if (bid < 256) {
        __shared__ float sf[64 * 68];
        const int b = bid >> 7, h = (bid >> 4) & 7, m0 = (bid & 15) * 64;
        #pragma unroll
        for (int fi = 0; fi < 4; ++fi) {
            const int idx = fi * 256 + t, mr = idx >> 4, c4 = idx & 15;
            const float4 v4 = *(const float4*)&vals[
                (((size_t)b * 1024 + m0 + mr) * 8 + h) * 64 + c4 * 4];
            *(float4*)&sf[mr * 68 + c4 * 4] = v4;
        }
        __syncthreads();
        const int v = t >> 2, mo = t & 3;
        short8v o0, o1;
        #pragma unroll
        for (int i = 0; i < 8; ++i) o0[i] = f2bf(sf[(mo * 16 + i) * 68 + v]);
        #pragma unroll
        for (int i = 0; i < 8; ++i) o1[i] = f2bf(sf[(mo * 16 + 8 + i) * 68 + v]);
        const size_t ob = ((size_t)(b * 8 + h) * 64 + v) * 1024 + m0 + mo * 16;
        *(short8v*)&vt[ob] = o0;
        *(short8v*)&vt[ob + 8] = o1;
    } else {
        const int wi = bid - 256;            // 0..31, 8192 floats each
        #pragma unroll
        for (int k = 0; k < 8; ++k) {
            const int fidx = wi * 8192 + k * 1024 + t * 4;
            const float4 f4 = *(const float4*)&outw[fidx];
            short4v s; s[0] = f2bf(f4.x); s[1] = f2bf(f4.y);
                       s[2] = f2bf(f4.z); s[3] = f2bf(f4.w);
            *(short4v*)&wb[fidx] = s;
        }
    }
}

// ---------------------------------------------------------------- cheb_attn
// grid (64, 8, 2) = (qt of 16 q, h, b), block 512 (8 waves = 8 m-groups of 128).
// LDS union: main {kp SoA + mask} 13.3KB | epilogue {pb[8] + l1[8]} 35.3KB.
#define LDS_BYTES 35328
__global__ __launch_bounds__(512, 8) void cheb_attn(
    const float* __restrict__ qp, const float* __restrict__ kp,
    const unsigned char* __restrict__ msk,
    const float* __restrict__ ls, const float* __restrict__ cheb,
    const short* __restrict__ vt, short* __restrict__ flatb)
{
    __shared__ __align__(16) unsigned char smem[LDS_BYTES];
    float* s_kx = (float*)smem;                    // [1024]
    float* s_ky = s_kx + 1024;                     // [1024]
    float* s_kz = s_ky + 1024;                     // [1024]
    unsigned char* s_mask = (unsigned char*)(s_kz + 1024);   // [1024]
    float* s_pb = (float*)smem;                    // epilogue: [8][16*68]
    float* s_l1 = s_pb + 8 * 16 * 68;              // epilogue: [8][16]

    const int t = threadIdx.x;
    const int qt = blockIdx.x, h = blockIdx.y, b = blockIdx.z;
    const int w = t >> 6, lane = t & 63;
    const int g = w;                               // m group (128 m)
    const int arow = lane & 15, koct = lane >> 4;

    // stage kp (SoA) + mask
    #pragma unroll
    for (int mm_ = 0; mm_ < 2; ++mm_) {
        const int m = mm_ * 512 + t;
        const size_t base = ((size_t)b * 1024 + m) * 3;
        s_kx[m] = kp[base + 0];
        s_ky[m] = kp[base + 1];
        s_kz[m] = kp[base + 2];
    }
    *(unsigned short*)&s_mask[t * 2] =
        *(const unsigned short*)&msk[(size_t)b * 1024 + t * 2];

    // per-head constants (wave-uniform -> scalar regs). Verified numerics.
    const float lsv = ls[h];
    const float invls2 = 1.0f / (lsv * lsv);
    float cc[8]; float cs = 0.f;
    #pragma unroll
    for (int j = 0; j < 8; ++j) { cc[j] = cheb[h * 8 + j]; cs += cc[j]; }
    const float cm = cs * 0.125f;
    #pragma unroll
    for (int j = 0; j < 8; ++j) cc[j] -= cm;

    // this lane's q row (A-fragment row identity)
    const int qg = qt * 16 + arow;
    const float qx = qp[((size_t)b * 1024 + qg) * 3 + 0];
    const float qy = qp[((size_t)b * 1024 + qg) * 3 + 1];
    const float qz = qp[((size_t)b * 1024 + qg) * 3 + 2];

    f32x4 acc[4] = {(f32x4)(0.f), (f32x4)(0.f), (f32x4)(0.f), (f32x4)(0.f)};
    const short* vtb = vt + ((size_t)(b * 8 + h) * 64) * 1024;
    float l1p = 0.f;

    __syncthreads();   // kp/mask staged

    #pragma unroll
    for (int tile = 0; tile < 2; ++tile) {
        const int m0 = g * 128 + tile * 64;

        // ---- 1) issue Vt B-frag loads (L2) — consumed only at step 3
        short8v bfr[2][4];
        #pragma unroll
        for (int kk = 0; kk < 2; ++kk)
            #pragma unroll
            for (int f = 0; f < 4; ++f)
                bfr[kk][f] = *(const short8v*)
                    &vtb[(size_t)(f * 16 + arow) * 1024 + m0 + kk * 32 + koct * 8];

        // ---- 1b) issue LDS k reads + mask for both kk groups
        f32x4 kx[2][2], ky[2][2], kz[2][2];
        uint2 mmv[2];
        #pragma unroll
        for (int kk = 0; kk < 2; ++kk) {
            const int mb = m0 + kk * 32 + koct * 8;
            kx[kk][0] = *(const f32x4*)&s_kx[mb]; kx[kk][1] = *(const f32x4*)&s_kx[mb + 4];
            ky[kk][0] = *(const f32x4*)&s_ky[mb]; ky[kk][1] = *(const f32x4*)&s_ky[mb + 4];
            kz[kk][0] = *(const f32x4*)&s_kz[mb]; kz[kk][1] = *(const f32x4*)&s_kz[mb + 4];
            mmv[kk] = *(const uint2*)&s_mask[mb];
        }

        // ---- 2) 16 scores, verified Chebyshev-recurrence numerics
        short8v a[2];
        #pragma unroll
        for (int kk = 0; kk < 2; ++kk) {
            const bool anymask = (mmv[kk].x | mmv[kk].y) != 0u;
            #pragma unroll
            for (int j = 0; j < 8; ++j) {
                const float dx = qx - kx[kk][j >> 2][j & 3];
                const float dy = qy - ky[kk][j >> 2][j & 3];
                const float dz = qz - kz[kk][j >> 2][j & 3];
                const float x  = (dx * dx + dy * dy + dz * dz) * invls2;
                const float r  = (x - 1.f) * frcp(x + 1.f);
                const float r2 = r + r;
                float tp = 1.f, tc = r;
                float s  = cc[0] + cc[1] * r;
                #pragma unroll
                for (int c = 2; c < 8; ++c) {
                    const float tn = r2 * tc - tp;
                    s += cc[c] * tn; tp = tc; tc = tn;
                }
                if (anymask) {
                    const unsigned int mword = (j < 4) ? mmv[kk].x : mmv[kk].y;
                    if ((mword >> ((j & 3) * 8)) & 0xffu) s = 0.f;
                }
                l1p += fabsf(s);
                a[kk][j] = f2bf(s);
            }
        }

        // ---- 3) attend
        #pragma unroll
        for (int kk = 0; kk < 2; ++kk)
            #pragma unroll
            for (int f = 0; f < 4; ++f)
                acc[f] = __builtin_amdgcn_mfma_f32_16x16x32_bf16(
                    a[kk], bfr[kk][f], acc[f], 0, 0, 0);
    }

    // L1 partial: lanes {arow, arow+16, arow+32, arow+48} share q row
    l1p += __shfl_xor(l1p, 16);
    l1p += __shfl_xor(l1p, 32);

    __syncthreads();   // all waves done with kp — union flips to epilogue view

    if (koct == 0) s_l1[g * 16 + arow] = l1p;
    #pragma unroll
    for (int f = 0; f < 4; ++f)
        #pragma unroll
        for (int j = 0; j < 4; ++j)
            s_pb[(g * 16 * 68) + (koct * 4 + j) * 68 + f * 16 + arow] = acc[f][j];
    __syncthreads();

    // 16 rows x 64 cols = 1024 outputs over 512 threads (2 each).
    #pragma unroll
    for (int v = 0; v < 2; ++v) {
        const int vid = v * 512 + t;
        const int row = vid >> 6, col = vid & 63;
        float den = s_l1[row];                     // g=0
        #pragma unroll
        for (int gg = 1; gg < 8; ++gg) den += s_l1[gg * 16 + row];
        const float rden = frcp(den + EPSF);
        float sum = s_pb[row * 68 + col];          // g=0
        #pragma unroll
        for (int gg = 1; gg < 8; ++gg) sum += s_pb[gg * 16 * 68 + row * 68 + col];
        flatb[((size_t)b * 1024 + qt * 16 + row) * 512 + h * 64 + col]
            = f2bf(sum * rden);
    }
}

// ---------------------------------------------------------------- proj
// out[2048,512] = flat[2048,512] @ Wb[n,k]^T, bf16 MFMA, frags direct from
// L2-resident global. grid (32,16): 64 rows x 32 n per block; block 256.
__global__ __launch_bounds__(256, 4) void proj(
    const short* __restrict__ flatb, const short* __restrict__ wb,
    float* __restrict__ out)
{
    const int t = threadIdx.x;
    const int r0 = blockIdx.x * 64, n0 = blockIdx.y * 32;
    const int w = t >> 6, lane = t & 63;
    const int arow = lane & 15, koct = lane >> 4;
    const int band = w * 16;

    f32x4 acc[2] = {(f32x4)(0.f), (f32x4)(0.f)};
    const short* ap = &flatb[(size_t)(r0 + band + arow) * 512];
    const short* b0 = &wb[(size_t)(n0 + arow) * 512];
    const short* b1 = &wb[(size_t)(n0 + 16 + arow) * 512];

    #pragma unroll 8
    for (int kk = 0; kk < 16; ++kk) {
        const int ko = kk * 32 + koct * 8;
        const short8v a   = *(const short8v*)&ap[ko];
        const short8v bf0 = *(const short8v*)&b0[ko];
        const short8v bf1 = *(const short8v*)&b1[ko];
        acc[0] = __builtin_amdgcn_mfma_f32_16x16x32_bf16(a, bf0, acc[0], 0, 0, 0);
        acc[1] = __builtin_amdgcn_mfma_f32_16x16x32_bf16(a, bf1, acc[1], 0, 0, 0);
    }
    #pragma unroll
    for (int f = 0; f < 2; ++f)
        #pragma unroll
        for (int j = 0; j < 4; ++j)
            out[((size_t)(r0 + band + koct * 4 + j)) * 512 + n0 + f * 16 + arow]
                = acc[f][j];
}

extern "C" void kernel_launch(void* const* d_in, const int* in_sizes, int n_in,
                              void* d_out, int out_size, void* d_ws, size_t ws_size,
                              hipStream_t stream) {
    const float* qp   = (const float*)d_in[0];
    const float* kp   = (const float*)d_in[1];
    const float* vals = (const float*)d_in[2];
    const unsigned char* msk = (const unsigned char*)d_in[3];
    const float* ls   = (const float*)d_in[4];
    const float* cheb = (const float*)d_in[5];
    const float* outw = (const float*)d_in[6];
    float* out = (float*)d_out;

    short* vtp   = (short*)d_ws;
    short* wbp   = vtp + WB_OFF_S;
    short* flatb = vtp + FLAT_OFF_S;

    prep<<<288, 256, 0, stream>>>(vals, outw, vtp, wbp);
    cheb_attn<<<dim3(64, 8, 2), 512, 0, stream>>>(qp, kp, msk, ls, cheb, vtp, flatb);
    proj<<<dim3(32, 16), 256, 0, stream>>>(flatb, wbp, out);
}

// Round 9
// 44.285 us; speedup vs baseline: 2.5595x; 1.3159x over previous
//
#include <hip/hip_runtime.h>
#include <hip/hip_bf16.h>

// LearnableChebyshevKernelAttention, MI355X — 2-dispatch version (prep folded
// into consumers; every cross-phase edge stays on a dispatch boundary — fusion
// via grid.sync/fences measured +70..+120us due to cross-XCD L2 coherence).
// cheb hot loop is the verified R3 structure (40.8us; occupancy lever closed:
// R8 proved the loop needs ~100 VGPR, 8 waves/SIMD spills). V fragments are
// built directly from vals f32 with in-register f2bf — bit-identical to the
// old prep->Vt path (same RNE on same floats, same MFMA order). proj converts
// its W rows f32->bf16 on the fly (same property).
// B=2, Q=M=1024, DIM=3, H=8, V=64, OUT=512, C=8.

typedef __attribute__((ext_vector_type(8))) short short8v;
typedef __attribute__((ext_vector_type(4))) float f32x4;

#define EPSF 1e-5f

__device__ __forceinline__ float frcp(float x) { return __builtin_amdgcn_rcpf(x); }
__device__ __forceinline__ short f2bf(float f) {
    __hip_bfloat16 h = __float2bfloat16(f);   // RNE
    return *reinterpret_cast<short*>(&h);
}

// ws layout (shorts): flat bf16 [2*1024*512] @ 0
// ---------------------------------------------------------------- cheb_attn
// grid (32, 8, 2) = (qt, h, b), block 512 (8 waves), 2 blocks/CU.
__global__ __launch_bounds__(512, 4) void cheb_attn(
    const float* __restrict__ qp, const float* __restrict__ kp,
    const unsigned char* __restrict__ msk,
    const float* __restrict__ ls, const float* __restrict__ cheb,
    const float* __restrict__ vals, short* __restrict__ flatb)
{
    __shared__ float s_kx[1024], s_ky[1024], s_kz[1024];   // kp SoA
    __shared__ __align__(8) unsigned char s_mask[1024];
    __shared__ float s_l1[4][32];
    __shared__ float s_pb[3][32 * 68];                      // groups 1..3 partial P

    const int t = threadIdx.x;
    const int qt = blockIdx.x, h = blockIdx.y, b = blockIdx.z;
    const int w = t >> 6, lane = t & 63;
    const int wg = w & 1, g = w >> 1;          // q band (16 rows), m group (256 m)
    const int arow = lane & 15, koct = lane >> 4;

    // stage kp (SoA) + mask
    #pragma unroll
    for (int mm_ = 0; mm_ < 2; ++mm_) {
        const int m = mm_ * 512 + t;
        const size_t base = ((size_t)b * 1024 + m) * 3;
        s_kx[m] = kp[base + 0];
        s_ky[m] = kp[base + 1];
        s_kz[m] = kp[base + 2];
    }
    *(unsigned short*)&s_mask[t * 2] =
        *(const unsigned short*)&msk[(size_t)b * 1024 + t * 2];

    // per-head constants (wave-uniform -> scalar regs). Verified numerics.
    const float lsv = ls[h];
    const float invls2 = 1.0f / (lsv * lsv);
    float cc[8]; float cs = 0.f;
    #pragma unroll
    for (int j = 0; j < 8; ++j) { cc[j] = cheb[h * 8 + j]; cs += cc[j]; }
    const float cm = cs * 0.125f;
    #pragma unroll
    for (int j = 0; j < 8; ++j) cc[j] -= cm;

    // this lane's q row (A-fragment row identity)
    const int qg = qt * 32 + wg * 16 + arow;
    const float qx = qp[((size_t)b * 1024 + qg) * 3 + 0];
    const float qy = qp[((size_t)b * 1024 + qg) * 3 + 1];
    const float qz = qp[((size_t)b * 1024 + qg) * 3 + 2];

    f32x4 acc[4] = {(f32x4)(0.f), (f32x4)(0.f), (f32x4)(0.f), (f32x4)(0.f)};
    // V plane base: element (m, v) at vpl[m*512 + v], v = h*64 + vcol
    const float* vpl = vals + (size_t)b * 1024 * 512 + h * 64;
    float l1p = 0.f;

    __syncthreads();   // kp/mask staged — the ONLY pre-epilogue barrier

    #pragma unroll
    for (int tile = 0; tile < 4; ++tile) {
        const int m0 = g * 256 + tile * 64;

        // ---- 1) LDS k reads + mask for both kk groups
        f32x4 kx[2][2], ky[2][2], kz[2][2];
        uint2 mmv[2];
        #pragma unroll
        for (int kk = 0; kk < 2; ++kk) {
            const int mb = m0 + kk * 32 + koct * 8;
            kx[kk][0] = *(const f32x4*)&s_kx[mb]; kx[kk][1] = *(const f32x4*)&s_kx[mb + 4];
            ky[kk][0] = *(const f32x4*)&s_ky[mb]; ky[kk][1] = *(const f32x4*)&s_ky[mb + 4];
            kz[kk][0] = *(const f32x4*)&s_kz[mb]; kz[kk][1] = *(const f32x4*)&s_kz[mb + 4];
            mmv[kk] = *(const uint2*)&s_mask[mb];
        }

        // ---- 2) 16 scores, verified Chebyshev-recurrence numerics
        short8v a[2];
        #pragma unroll
        for (int kk = 0; kk < 2; ++kk) {
            const bool anymask = (mmv[kk].x | mmv[kk].y) != 0u;
            #pragma unroll
            for (int j = 0; j < 8; ++j) {
                const float dx = qx - kx[kk][j >> 2][j & 3];
                const float dy = qy - ky[kk][j >> 2][j & 3];
                const float dz = qz - kz[kk][j >> 2][j & 3];
                const float x  = (dx * dx + dy * dy + dz * dz) * invls2;
                const float r  = (x - 1.f) * frcp(x + 1.f);
                const float r2 = r + r;
                float tp = 1.f, tc = r;
                float s  = cc[0] + cc[1] * r;
                #pragma unroll
                for (int c = 2; c < 8; ++c) {
                    const float tn = r2 * tc - tp;
                    s += cc[c] * tn; tp = tc; tc = tn;
                }
                if (anymask) {
                    const unsigned int mword = (j < 4) ? mmv[kk].x : mmv[kk].y;
                    if ((mword >> ((j & 3) * 8)) & 0xffu) s = 0.f;
                }
                l1p += fabsf(s);
                a[kk][j] = f2bf(s);
            }
        }

        // ---- 3) attend: B-frags built directly from vals f32 (bit-identical
        //         to the old prep->Vt bf16 path: same f2bf on same floats)
        #pragma unroll
        for (int kk = 0; kk < 2; ++kk) {
            const float* vb = vpl + (size_t)(m0 + kk * 32 + koct * 8) * 512 + arow;
            #pragma unroll
            for (int f = 0; f < 4; ++f) {
                short8v bfv;
                #pragma unroll
                for (int j = 0; j < 8; ++j)
                    bfv[j] = f2bf(vb[j * 512 + f * 16]);
                acc[f] = __builtin_amdgcn_mfma_f32_16x16x32_bf16(
                    a[kk], bfv, acc[f], 0, 0, 0);
            }
        }
    }

    // L1 partial: lanes {arow, arow+16, arow+32, arow+48} share q row
    l1p += __shfl_xor(l1p, 16);
    l1p += __shfl_xor(l1p, 32);
    if (koct == 0) s_l1[g][wg * 16 + arow] = l1p;

    if (g > 0) {
        #pragma unroll
        for (int f = 0; f < 4; ++f)
            #pragma unroll
            for (int j = 0; j < 4; ++j)
                s_pb[g - 1][(wg * 16 + koct * 4 + j) * 68 + f * 16 + arow] = acc[f][j];
    }
    __syncthreads();
    if (g == 0) {
        float rden[4];
        #pragma unroll
        for (int j = 0; j < 4; ++j) {
            const int row = wg * 16 + koct * 4 + j;
            rden[j] = frcp(s_l1[0][row] + s_l1[1][row] + s_l1[2][row]
                         + s_l1[3][row] + EPSF);
        }
        #pragma unroll
        for (int f = 0; f < 4; ++f)
            #pragma unroll
            for (int j = 0; j < 4; ++j) {
                const int row = wg * 16 + koct * 4 + j;
                const int col = f * 16 + arow;
                const float v = (acc[f][j]
                    + s_pb[0][row * 68 + col]
                    + s_pb[1][row * 68 + col]
                    + s_pb[2][row * 68 + col]) * rden[j];
                flatb[((size_t)b * 1024 + qt * 32 + row) * 512 + h * 64 + col]
                    = f2bf(v);
            }
    }
}

// ---------------------------------------------------------------- proj
// out[2048,512] = flat[2048,512] @ W[n,k]^T; W converted f32->bf16 on the fly
// (bit-identical to old prep conversion). grid (32,16): 64 rows x 32 n per
// block; block 256 (4 waves).
__global__ __launch_bounds__(256, 4) void proj(
    const short* __restrict__ flatb, const float* __restrict__ outw,
    float* __restrict__ out)
{
    const int t = threadIdx.x;
    const int r0 = blockIdx.x * 64, n0 = blockIdx.y * 32;
    const int w = t >> 6, lane = t & 63;
    const int arow = lane & 15, koct = lane >> 4;
    const int band = w * 16;

    f32x4 acc[2] = {(f32x4)(0.f), (f32x4)(0.f)};
    const short* ap = &flatb[(size_t)(r0 + band + arow) * 512];
    const float* w0 = &outw[(size_t)(n0 + arow) * 512];
    const float* w1 = &outw[(size_t)(n0 + 16 + arow) * 512];

    #pragma unroll 8
    for (int kk = 0; kk < 16; ++kk) {
        const int ko = kk * 32 + koct * 8;
        const short8v a = *(const short8v*)&ap[ko];
        const float4 wa0 = *(const float4*)&w0[ko];
        const float4 wb0 = *(const float4*)&w0[ko + 4];
        const float4 wa1 = *(const float4*)&w1[ko];
        const float4 wb1 = *(const float4*)&w1[ko + 4];
        short8v bf0, bf1;
        bf0[0] = f2bf(wa0.x); bf0[1] = f2bf(wa0.y); bf0[2] = f2bf(wa0.z); bf0[3] = f2bf(wa0.w);
        bf0[4] = f2bf(wb0.x); bf0[5] = f2bf(wb0.y); bf0[6] = f2bf(wb0.z); bf0[7] = f2bf(wb0.w);
        bf1[0] = f2bf(wa1.x); bf1[1] = f2bf(wa1.y); bf1[2] = f2bf(wa1.z); bf1[3] = f2bf(wa1.w);
        bf1[4] = f2bf(wb1.x); bf1[5] = f2bf(wb1.y); bf1[6] = f2bf(wb1.z); bf1[7] = f2bf(wb1.w);
        acc[0] = __builtin_amdgcn_mfma_f32_16x16x32_bf16(a, bf0, acc[0], 0, 0, 0);
        acc[1] = __builtin_amdgcn_mfma_f32_16x16x32_bf16(a, bf1, acc[1], 0, 0, 0);
    }
    #pragma unroll
    for (int f = 0; f < 2; ++f)
        #pragma unroll
        for (int j = 0; j < 4; ++j)
            out[((size_t)(r0 + band + koct * 4 + j)) * 512 + n0 + f * 16 + arow]
                = acc[f][j];
}

extern "C" void kernel_launch(void* const* d_in, const int* in_sizes, int n_in,
                              void* d_out, int out_size, void* d_ws, size_t ws_size,
                              hipStream_t stream) {
    const float* qp   = (const float*)d_in[0];
    const float* kp   = (const float*)d_in[1];
    const float* vals = (const float*)d_in[2];
    const unsigned char* msk = (const unsigned char*)d_in[3];
    const float* ls   = (const float*)d_in[4];
    const float* cheb = (const float*)d_in[5];
    const float* outw = (const float*)d_in[6];
    float* out = (float*)d_out;

    short* flatb = (short*)d_ws;

    cheb_attn<<<dim3(32, 8, 2), 512, 0, stream>>>(qp, kp, msk, ls, cheb, vals, flatb);
    proj<<<dim3(32, 16), 256, 0, stream>>>(flatb, outw, out);
}

// Round 10
// 42.100 us; speedup vs baseline: 2.6923x; 1.0519x over previous
//
#include <hip/hip_runtime.h>
#include <hip/hip_bf16.h>

// LearnableChebyshevKernelAttention, MI355X — three-dispatch chain.
// prep/proj: verified R3 versions. cheb: R8 geometry (1024 half-blocks,
// 8 waves/SIMD target) with the R8 spill bug fixed: __launch_bounds__(512,4)
// (NOT (512,8) — that capped VGPR at 64, allocator squeezed to 32 and spilled
// 136MB). Hot loop compiles to ~60 VGPR => HW grants 32 waves/CU on its own;
// LDS union {kp SoA | epilogue partials} = 35.3KB => 4 blocks/CU fit.
// Score numerics BYTE-IDENTICAL to verified R3; 8-partial epilogue
// reassociation pre-verified by R8 (passed, absmax unchanged).
// B=2, Q=M=1024, DIM=3, H=8, V=64, OUT=512, C=8.

typedef __attribute__((ext_vector_type(8))) short short8v;
typedef __attribute__((ext_vector_type(4))) short short4v;
typedef __attribute__((ext_vector_type(4))) float f32x4;

#define EPSF 1e-5f

__device__ __forceinline__ float frcp(float x) { return __builtin_amdgcn_rcpf(x); }
__device__ __forceinline__ short f2bf(float f) {
    __hip_bfloat16 h = __float2bfloat16(f);   // RNE
    return *reinterpret_cast<short*>(&h);
}

// ws layout (shorts): Vt bf16 [2*8*64*1024] | Wb bf16 [512*512] | flat bf16 [2*1024*512]
#define VT_ELEMS   (2u * 8u * 64u * 1024u)
#define WB_OFF_S   (VT_ELEMS)
#define FLAT_OFF_S (VT_ELEMS + 512u * 512u)

// ---------------------------------------------------------------- prep
// grid 288: blocks 0..255 transpose one (b,h,64m) values tile; 256..287 convert W.
__global__ __launch_bounds__(256) void prep(
    const float* __restrict__ vals, const float* __restrict__ outw,
    short* __restrict__ vt, short* __restrict__ wb)
{
    const int bid = blockIdx.x, t = threadIdx.x;
    if (bid < 256) {
        __shared__ float sf[64 * 68];
        const int b = bid >> 7, h = (bid >> 4) & 7, m0 = (bid & 15) * 64;
        #pragma unroll
        for (int fi = 0; fi < 4; ++fi) {
            const int idx = fi * 256 + t, mr = idx >> 4, c4 = idx & 15;
            const float4 v4 = *(const float4*)&vals[
                (((size_t)b * 1024 + m0 + mr) * 8 + h) * 64 + c4 * 4];
            *(float4*)&sf[mr * 68 + c4 * 4] = v4;
        }
        __syncthreads();
        const int v = t >> 2, mo = t & 3;
        short8v o0, o1;
        #pragma unroll
        for (int i = 0; i < 8; ++i) o0[i] = f2bf(sf[(mo * 16 + i) * 68 + v]);
        #pragma unroll
        for (int i = 0; i < 8; ++i) o1[i] = f2bf(sf[(mo * 16 + 8 + i) * 68 + v]);
        const size_t ob = ((size_t)(b * 8 + h) * 64 + v) * 1024 + m0 + mo * 16;
        *(short8v*)&vt[ob] = o0;
        *(short8v*)&vt[ob + 8] = o1;
    } else {
        const int wi = bid - 256;            // 0..31, 8192 floats each
        #pragma unroll
        for (int k = 0; k < 8; ++k) {
            const int fidx = wi * 8192 + k * 1024 + t * 4;
            const float4 f4 = *(const float4*)&outw[fidx];
            short4v s; s[0] = f2bf(f4.x); s[1] = f2bf(f4.y);
                       s[2] = f2bf(f4.z); s[3] = f2bf(f4.w);
            *(short4v*)&wb[fidx] = s;
        }
    }
}

// ---------------------------------------------------------------- cheb_attn
// grid (64, 8, 2) = (qt of 16 q, h, b), block 512 (8 waves = 8 m-groups of 128).
// LDS union: main {kp SoA + mask} 13.3KB | epilogue {pb[8] + l1[8]} 35.3KB.
#define LDS_BYTES 35328
__global__ __launch_bounds__(512, 4) void cheb_attn(
    const float* __restrict__ qp, const float* __restrict__ kp,
    const unsigned char* __restrict__ msk,
    const float* __restrict__ ls, const float* __restrict__ cheb,
    const short* __restrict__ vt, short* __restrict__ flatb)
{
    __shared__ __align__(16) unsigned char smem[LDS_BYTES];
    float* s_kx = (float*)smem;                    // [1024]
    float* s_ky = s_kx + 1024;                     // [1024]
    float* s_kz = s_ky + 1024;                     // [1024]
    unsigned char* s_mask = (unsigned char*)(s_kz + 1024);   // [1024]
    float* s_pb = (float*)smem;                    // epilogue: [8][16*68]
    float* s_l1 = s_pb + 8 * 16 * 68;              // epilogue: [8][16]

    const int t = threadIdx.x;
    const int qt = blockIdx.x, h = blockIdx.y, b = blockIdx.z;
    const int w = t >> 6, lane = t & 63;
    const int g = w;                               // m group (128 m)
    const int arow = lane & 15, koct = lane >> 4;

    // stage kp (SoA) + mask
    #pragma unroll
    for (int mm_ = 0; mm_ < 2; ++mm_) {
        const int m = mm_ * 512 + t;
        const size_t base = ((size_t)b * 1024 + m) * 3;
        s_kx[m] = kp[base + 0];
        s_ky[m] = kp[base + 1];
        s_kz[m] = kp[base + 2];
    }
    *(unsigned short*)&s_mask[t * 2] =
        *(const unsigned short*)&msk[(size_t)b * 1024 + t * 2];

    // per-head constants (wave-uniform -> scalar regs). Verified numerics.
    const float lsv = ls[h];
    const float invls2 = 1.0f / (lsv * lsv);
    float cc[8]; float cs = 0.f;
    #pragma unroll
    for (int j = 0; j < 8; ++j) { cc[j] = cheb[h * 8 + j]; cs += cc[j]; }
    const float cm = cs * 0.125f;
    #pragma unroll
    for (int j = 0; j < 8; ++j) cc[j] -= cm;

    // this lane's q row (A-fragment row identity)
    const int qg = qt * 16 + arow;
    const float qx = qp[((size_t)b * 1024 + qg) * 3 + 0];
    const float qy = qp[((size_t)b * 1024 + qg) * 3 + 1];
    const float qz = qp[((size_t)b * 1024 + qg) * 3 + 2];

    f32x4 acc[4] = {(f32x4)(0.f), (f32x4)(0.f), (f32x4)(0.f), (f32x4)(0.f)};
    const short* vtb = vt + ((size_t)(b * 8 + h) * 64) * 1024;
    float l1p = 0.f;

    __syncthreads();   // kp/mask staged

    #pragma unroll
    for (int tile = 0; tile < 2; ++tile) {
        const int m0 = g * 128 + tile * 64;

        // ---- 1) issue Vt B-frag loads (L2) — consumed only at step 3
        short8v bfr[2][4];
        #pragma unroll
        for (int kk = 0; kk < 2; ++kk)
            #pragma unroll
            for (int f = 0; f < 4; ++f)
                bfr[kk][f] = *(const short8v*)
                    &vtb[(size_t)(f * 16 + arow) * 1024 + m0 + kk * 32 + koct * 8];

        // ---- 1b) issue LDS k reads + mask for both kk groups
        f32x4 kx[2][2], ky[2][2], kz[2][2];
        uint2 mmv[2];
        #pragma unroll
        for (int kk = 0; kk < 2; ++kk) {
            const int mb = m0 + kk * 32 + koct * 8;
            kx[kk][0] = *(const f32x4*)&s_kx[mb]; kx[kk][1] = *(const f32x4*)&s_kx[mb + 4];
            ky[kk][0] = *(const f32x4*)&s_ky[mb]; ky[kk][1] = *(const f32x4*)&s_ky[mb + 4];
            kz[kk][0] = *(const f32x4*)&s_kz[mb]; kz[kk][1] = *(const f32x4*)&s_kz[mb + 4];
            mmv[kk] = *(const uint2*)&s_mask[mb];
        }

        // ---- 2) 16 scores, verified Chebyshev-recurrence numerics
        short8v a[2];
        #pragma unroll
        for (int kk = 0; kk < 2; ++kk) {
            const bool anymask = (mmv[kk].x | mmv[kk].y) != 0u;
            #pragma unroll
            for (int j = 0; j < 8; ++j) {
                const float dx = qx - kx[kk][j >> 2][j & 3];
                const float dy = qy - ky[kk][j >> 2][j & 3];
                const float dz = qz - kz[kk][j >> 2][j & 3];
                const float x  = (dx * dx + dy * dy + dz * dz) * invls2;
                const float r  = (x - 1.f) * frcp(x + 1.f);
                const float r2 = r + r;
                float tp = 1.f, tc = r;
                float s  = cc[0] + cc[1] * r;
                #pragma unroll
                for (int c = 2; c < 8; ++c) {
                    const float tn = r2 * tc - tp;
                    s += cc[c] * tn; tp = tc; tc = tn;
                }
                if (anymask) {
                    const unsigned int mword = (j < 4) ? mmv[kk].x : mmv[kk].y;
                    if ((mword >> ((j & 3) * 8)) & 0xffu) s = 0.f;
                }
                l1p += fabsf(s);
                a[kk][j] = f2bf(s);
            }
        }

        // ---- 3) attend
        #pragma unroll
        for (int kk = 0; kk < 2; ++kk)
            #pragma unroll
            for (int f = 0; f < 4; ++f)
                acc[f] = __builtin_amdgcn_mfma_f32_16x16x32_bf16(
                    a[kk], bfr[kk][f], acc[f], 0, 0, 0);
    }

    // L1 partial: lanes {arow, arow+16, arow+32, arow+48} share q row
    l1p += __shfl_xor(l1p, 16);
    l1p += __shfl_xor(l1p, 32);

    __syncthreads();   // all waves done with kp — union flips to epilogue view

    if (koct == 0) s_l1[g * 16 + arow] = l1p;
    #pragma unroll
    for (int f = 0; f < 4; ++f)
        #pragma unroll
        for (int j = 0; j < 4; ++j)
            s_pb[(g * 16 * 68) + (koct * 4 + j) * 68 + f * 16 + arow] = acc[f][j];
    __syncthreads();

    // 16 rows x 64 cols = 1024 outputs over 512 threads (2 each).
    #pragma unroll
    for (int v = 0; v < 2; ++v) {
        const int vid = v * 512 + t;
        const int row = vid >> 6, col = vid & 63;
        float den = s_l1[row];                     // g=0
        #pragma unroll
        for (int gg = 1; gg < 8; ++gg) den += s_l1[gg * 16 + row];
        const float rden = frcp(den + EPSF);
        float sum = s_pb[row * 68 + col];          // g=0
        #pragma unroll
        for (int gg = 1; gg < 8; ++gg) sum += s_pb[gg * 16 * 68 + row * 68 + col];
        flatb[((size_t)b * 1024 + qt * 16 + row) * 512 + h * 64 + col]
            = f2bf(sum * rden);
    }
}

// ---------------------------------------------------------------- proj
// out[2048,512] = flat[2048,512] @ Wb[n,k]^T, bf16 MFMA, frags direct from
// L2-resident global. grid (32,16): 64 rows x 32 n per block; block 256.
__global__ __launch_bounds__(256, 4) void proj(
    const short* __restrict__ flatb, const short* __restrict__ wb,
    float* __restrict__ out)
{
    const int t = threadIdx.x;
    const int r0 = blockIdx.x * 64, n0 = blockIdx.y * 32;
    const int w = t >> 6, lane = t & 63;
    const int arow = lane & 15, koct = lane >> 4;
    const int band = w * 16;

    f32x4 acc[2] = {(f32x4)(0.f), (f32x4)(0.f)};
    const short* ap = &flatb[(size_t)(r0 + band + arow) * 512];
    const short* b0 = &wb[(size_t)(n0 + arow) * 512];
    const short* b1 = &wb[(size_t)(n0 + 16 + arow) * 512];

    #pragma unroll 8
    for (int kk = 0; kk < 16; ++kk) {
        const int ko = kk * 32 + koct * 8;
        const short8v a   = *(const short8v*)&ap[ko];
        const short8v bf0 = *(const short8v*)&b0[ko];
        const short8v bf1 = *(const short8v*)&b1[ko];
        acc[0] = __builtin_amdgcn_mfma_f32_16x16x32_bf16(a, bf0, acc[0], 0, 0, 0);
        acc[1] = __builtin_amdgcn_mfma_f32_16x16x32_bf16(a, bf1, acc[1], 0, 0, 0);
    }
    #pragma unroll
    for (int f = 0; f < 2; ++f)
        #pragma unroll
        for (int j = 0; j < 4; ++j)
            out[((size_t)(r0 + band + koct * 4 + j)) * 512 + n0 + f * 16 + arow]
                = acc[f][j];
}

extern "C" void kernel_launch(void* const* d_in, const int* in_sizes, int n_in,
                              void* d_out, int out_size, void* d_ws, size_t ws_size,
                              hipStream_t stream) {
    const float* qp   = (const float*)d_in[0];
    const float* kp   = (const float*)d_in[1];
    const float* vals = (const float*)d_in[2];
    const unsigned char* msk = (const unsigned char*)d_in[3];
    const float* ls   = (const float*)d_in[4];
    const float* cheb = (const float*)d_in[5];
    const float* outw = (const float*)d_in[6];
    float* out = (float*)d_out;

    short* vtp   = (short*)d_ws;
    short* wbp   = vtp + WB_OFF_S;
    short* flatb = vtp + FLAT_OFF_S;

    prep<<<288, 256, 0, stream>>>(vals, outw, vtp, wbp);
    cheb_attn<<<dim3(64, 8, 2), 512, 0, stream>>>(qp, kp, msk, ls, cheb, vtp, flatb);
    proj<<<dim3(32, 16), 256, 0, stream>>>(flatb, wbp, out);
}